// Round 4
// baseline (754.684 us; speedup 1.0000x reference)
//
#include <hip/hip_runtime.h>

// ---------------- types & helpers ----------------
typedef __attribute__((ext_vector_type(4))) float  f32x4;
typedef __attribute__((ext_vector_type(8))) short  s16x8;

__device__ __forceinline__ short f2bf(float f) {
    unsigned u = __builtin_bit_cast(unsigned, f);
    u += 0x7FFFu + ((u >> 16) & 1u);            // round-to-nearest-even
    return (short)(u >> 16);
}
__device__ __forceinline__ float bf2f(short s) {
    unsigned u = ((unsigned)(unsigned short)s) << 16;
    return __builtin_bit_cast(float, u);
}

#define DEPTH 128   // D == H*C == 128
#define HEADS 8
#define TILE_M 64
#define NPB 8       // nodes per block (one per wave)

// ---------------- kernel 0: W -> bf16, transposed (Wt[c][k]) ----------------
// order: 0=Wq 1=Wk 2=Wv 3=We 4=Wskip
__global__ void prep_w(const float* __restrict__ Wq, const float* __restrict__ Wk,
                       const float* __restrict__ Wv, const float* __restrict__ We,
                       const float* __restrict__ Wsk, short* __restrict__ Wt5) {
    int idx = blockIdx.x * 256 + threadIdx.x;
    if (idx >= 5 * DEPTH * DEPTH) return;
    int mat = idx >> 14;
    int rem = idx & 16383;
    int k = rem >> 7, c = rem & 127;
    const float* W = (mat == 0) ? Wq : (mat == 1) ? Wk : (mat == 2) ? Wv : (mat == 3) ? We : Wsk;
    Wt5[mat * 16384 + c * 128 + k] = f2bf(W[k * 128 + c]);
}

// ---------------- shared GEMM pieces ----------------
#define LOAD_BFRAG(bfrag, Wt, wc, lane)                                         \
    _Pragma("unroll") for (int nt_ = 0; nt_ < 4; nt_++)                         \
    _Pragma("unroll") for (int kk_ = 0; kk_ < 4; kk_++) {                       \
        int col_ = (wc) + nt_ * 16 + ((lane) & 15);                             \
        int kidx_ = kk_ * 32 + ((lane) >> 4) * 8;                               \
        bfrag[nt_][kk_] = *(const s16x8*)&(Wt)[col_ * 128 + kidx_];             \
    }

// ---------------- kernel 1: node projections ----------------
// mat 0=q -> qb bf16 [N][128]; 1=k, 2=v -> kvb packed [N][256]:
// kvb[n*256 + cp*4 + {0,1}] = k channels {2cp, 2cp+1}, + {2,3} = v channels.
// mat 3 = skip -> skb f32.
__global__ __launch_bounds__(512, 1) void node_proj(
    const float* __restrict__ x, const short* __restrict__ Wt5,
    const float* __restrict__ bq, const float* __restrict__ bk,
    const float* __restrict__ bv, const float* __restrict__ bsk,
    short* __restrict__ qb, short* __restrict__ kvb,
    float* __restrict__ skb, int Nn) {
    int mat = blockIdx.y;
    const short* Wt = Wt5 + ((mat < 3) ? mat : 4) * 16384;
    const float* bias = (mat == 0) ? bq : (mat == 1) ? bk : (mat == 2) ? bv : bsk;

    __shared__ short Asm[TILE_M][136];
    int tid = threadIdx.x, wave = tid >> 6, lane = tid & 63;
    int row0 = blockIdx.x * TILE_M;

    for (int i_ = 0; i_ < 4; i_++) {
        int f_ = tid + i_ * 512;
        int r_ = f_ >> 5, c4_ = f_ & 31;
        int gr_ = row0 + r_;
        float4 v_ = (gr_ < Nn) ? ((const float4*)x)[(size_t)gr_ * 32 + c4_]
                               : make_float4(0.f, 0.f, 0.f, 0.f);
        short* d_ = &Asm[r_][c4_ * 4];
        d_[0] = f2bf(v_.x); d_[1] = f2bf(v_.y); d_[2] = f2bf(v_.z); d_[3] = f2bf(v_.w);
    }

    int wr = (wave >> 1) * 16, wc = (wave & 1) * 64;
    s16x8 bfrag[4][4];
    LOAD_BFRAG(bfrag, Wt, wc, lane);
    __syncthreads();

    f32x4 acc[4];
#pragma unroll
    for (int nt = 0; nt < 4; nt++) acc[nt] = (f32x4){0.f, 0.f, 0.f, 0.f};
#pragma unroll
    for (int kk = 0; kk < 4; kk++) {
        s16x8 a = *(const s16x8*)&Asm[wr + (lane & 15)][kk * 32 + (lane >> 4) * 8];
#pragma unroll
        for (int nt = 0; nt < 4; nt++)
            acc[nt] = __builtin_amdgcn_mfma_f32_16x16x32_bf16(a, bfrag[nt][kk], acc[nt], 0, 0, 0);
    }
#pragma unroll
    for (int nt = 0; nt < 4; nt++) {
        int col = wc + nt * 16 + (lane & 15);
        float b = bias[col];
#pragma unroll
        for (int i = 0; i < 4; i++) {
            int row = row0 + wr + (lane >> 4) * 4 + i;
            if (row < Nn) {
                float val = acc[nt][i] + b;
                if (mat == 0)      qb[(size_t)row * 128 + col] = f2bf(val);
                else if (mat == 1) kvb[(size_t)row * 256 + ((col >> 1) << 2) + (col & 1)] = f2bf(val);
                else if (mat == 2) kvb[(size_t)row * 256 + ((col >> 1) << 2) + 2 + (col & 1)] = f2bf(val);
                else               skb[(size_t)row * 128 + col] = val;
            }
        }
    }
}

// ---------------- CSR build ----------------
__global__ void hist_dst(const int* __restrict__ eidx, int* __restrict__ cnt, int Ee) {
    int e = blockIdx.x * 256 + threadIdx.x;
    if (e < Ee) atomicAdd(&cnt[eidx[Ee + e]], 1);
}

__global__ __launch_bounds__(1024, 1) void scan_rowptr(const int* __restrict__ cnt,
                                                       int* __restrict__ rowptr, int Nn) {
    __shared__ int part[1024];
    int t = threadIdx.x;
    int chunk = (Nn + 1023) / 1024;
    int b = t * chunk;
    int e = b + chunk; if (e > Nn) e = Nn;
    int sum = 0;
    for (int i = b; i < e && i < Nn; i++) sum += cnt[i];
    part[t] = sum;
    __syncthreads();
    for (int off = 1; off < 1024; off <<= 1) {
        int v = (t >= off) ? part[t - off] : 0;
        __syncthreads();
        part[t] += v;
        __syncthreads();
    }
    int run = part[t] - sum;   // exclusive
    for (int i = b; i < e && i < Nn; i++) { rowptr[i] = run; run += cnt[i]; }
    if (t == 1023) rowptr[Nn] = part[1023];
}

__global__ void fill_perm(const int* __restrict__ eidx, const int* __restrict__ rowptr,
                          int* __restrict__ cursor, int* __restrict__ perm, int Ee) {
    int e = blockIdx.x * 256 + threadIdx.x;
    if (e >= Ee) return;
    int d = eidx[Ee + e];
    int pos = atomicAdd(&cursor[d], 1);
    perm[rowptr[d] + pos] = e;
}

// ---------------- kernel 2: FUSED edge projection + softmax + PV ----------------
// Block owns NPB consecutive dst nodes (wave w -> node n0+w). Tiles of 64 edges
// from the block's CSR range: perm-gather ea -> MFMA e=ea@We -> each wave does
// online-softmax accumulation for its node. alpha/ve never touch HBM.
// LDS: Asm (bf16 input tile) and Es (f32 projection) share one 32KB buffer.
__global__ __launch_bounds__(512) void fused_attn(
    const float* __restrict__ ea, const short* __restrict__ Wt5,
    const short* __restrict__ qb, const short* __restrict__ kvb,
    const int* __restrict__ eidx, const int* __restrict__ perm,
    const int* __restrict__ rowptr, const float* __restrict__ skb,
    float* __restrict__ out, int Nn, int Ee) {
    const short* Wt = Wt5 + 3 * 16384;  // We

    __shared__ char smraw[TILE_M * DEPTH * 4];   // 32 KB, unioned
    __shared__ int Ss[TILE_M];
    short (*Asm)[136] = (short (*)[136])smraw;   // 17.4 KB used during MFMA
    float (*Es)[DEPTH] = (float (*)[DEPTH])smraw;

    int tid = threadIdx.x, wave = tid >> 6, lane = tid & 63;
    int n0 = blockIdx.x * NPB;
    int myNode = n0 + wave;
    int lastN = (n0 + NPB < Nn) ? n0 + NPB : Nn;
    int blkBeg = rowptr[n0];
    int blkEnd = rowptr[lastN];
    int myBeg = (myNode < Nn) ? rowptr[myNode] : 0;
    int myEnd = (myNode < Nn) ? rowptr[myNode + 1] : 0;

    // per-lane q for my node: channels 2*lane, 2*lane+1
    float q0 = 0.f, q1 = 0.f;
    if (myNode < Nn) {
        unsigned qq = *(const unsigned*)&qb[(size_t)myNode * 128 + lane * 2];
        q0 = bf2f((short)(qq & 0xffff));
        q1 = bf2f((short)(qq >> 16));
    }

    int wr = (wave >> 1) * 16, wc = (wave & 1) * 64;
    float m = -3.0e38f, s = 0.f, acc0 = 0.f, acc1 = 0.f;

    for (int t0 = blkBeg; t0 < blkEnd; t0 += TILE_M) {
        int cnt = blkEnd - t0; if (cnt > TILE_M) cnt = TILE_M;

        // ---- stage: src ids + ea rows (perm-gathered, 512B granular) ----
        if (tid < TILE_M)
            Ss[tid] = (tid < cnt) ? eidx[perm[t0 + tid]] : 0;
        for (int i_ = 0; i_ < 4; i_++) {
            int f_ = tid + i_ * 512;
            int r_ = f_ >> 5, c4_ = f_ & 31;
            float4 v_;
            if (r_ < cnt) {
                int pe = perm[t0 + r_];          // redundant across 32 lanes, L1-hot
                v_ = ((const float4*)ea)[(size_t)pe * 32 + c4_];
            } else v_ = make_float4(0.f, 0.f, 0.f, 0.f);
            short* d_ = &Asm[r_][c4_ * 4];
            d_[0] = f2bf(v_.x); d_[1] = f2bf(v_.y); d_[2] = f2bf(v_.z); d_[3] = f2bf(v_.w);
        }
        __syncthreads();

        // ---- MFMA: e = ea_tile @ We ----
        s16x8 bfrag[4][4];
        LOAD_BFRAG(bfrag, Wt, wc, lane);        // L1-resident 32KB, reload per tile
        f32x4 acc[4];
#pragma unroll
        for (int nt = 0; nt < 4; nt++) acc[nt] = (f32x4){0.f, 0.f, 0.f, 0.f};
#pragma unroll
        for (int kk = 0; kk < 4; kk++) {
            s16x8 a = *(const s16x8*)&Asm[wr + (lane & 15)][kk * 32 + (lane >> 4) * 8];
#pragma unroll
            for (int nt = 0; nt < 4; nt++)
                acc[nt] = __builtin_amdgcn_mfma_f32_16x16x32_bf16(a, bfrag[nt][kk], acc[nt], 0, 0, 0);
        }
        __syncthreads();   // Asm dead; reuse the buffer as Es

        // ---- write Es (overwrites Asm region) ----
#pragma unroll
        for (int nt = 0; nt < 4; nt++) {
            int col = wc + nt * 16 + (lane & 15);
#pragma unroll
            for (int i = 0; i < 4; i++)
                Es[wr + (lane >> 4) * 4 + i][col] = acc[nt][i];
        }
        __syncthreads();

        // ---- accumulate: wave w handles its node's edges inside this tile ----
        int lo = myBeg > t0 ? myBeg : t0;
        int hi = myEnd < t0 + cnt ? myEnd : t0 + cnt;
        for (int i = lo; i < hi; i++) {
            int eL = i - t0;
            int src = Ss[eL];
            uint2 kv = *(const uint2*)&kvb[(size_t)src * 256 + lane * 4];  // {k0,k1,v0,v1}
            float2 e2 = *(const float2*)&Es[eL][lane * 2];
            float k0 = bf2f((short)(kv.x & 0xffff)) + e2.x;
            float k1 = bf2f((short)(kv.x >> 16))    + e2.y;
            float partial = q0 * k0 + q1 * k1;
            // sum over the 8-lane group = one head (16 channels)
            partial += __shfl_xor(partial, 1);
            partial += __shfl_xor(partial, 2);
            partial += __shfl_xor(partial, 4);
            float a = partial * 0.25f;          // 1/sqrt(C), C=16
            float mn = fmaxf(m, a);
            float r = __expf(m - mn);
            float p = __expf(a - mn);
            s = s * r + p;
            float v0 = bf2f((short)(kv.y & 0xffff)) + e2.x;
            float v1 = bf2f((short)(kv.y >> 16))    + e2.y;
            acc0 = acc0 * r + p * v0;
            acc1 = acc1 * r + p * v1;
            m = mn;
        }
        __syncthreads();   // protect Es/Ss before next tile's staging
    }

    // ---- epilogue: out = acc/(s+eps) + skip ----
    if (myNode < Nn) {
        float inv = 1.f / (s + 1e-16f);
        size_t o = (size_t)myNode * 128 + lane * 2;
        float2 sk = *(const float2*)&skb[o];
        float2 res = make_float2(acc0 * inv + sk.x, acc1 * inv + sk.y);
        *(float2*)&out[o] = res;
    }
}

// ---------------- launch ----------------
extern "C" void kernel_launch(void* const* d_in, const int* in_sizes, int n_in,
                              void* d_out, int out_size, void* d_ws, size_t ws_size,
                              hipStream_t stream) {
    const float* x   = (const float*)d_in[0];
    const float* ea  = (const float*)d_in[1];
    const float* Wq  = (const float*)d_in[2];
    const float* bq  = (const float*)d_in[3];
    const float* Wk  = (const float*)d_in[4];
    const float* bk  = (const float*)d_in[5];
    const float* Wv  = (const float*)d_in[6];
    const float* bv  = (const float*)d_in[7];
    const float* We  = (const float*)d_in[8];
    const float* Wsk = (const float*)d_in[9];
    const float* bsk = (const float*)d_in[10];
    const int*   eidx = (const int*)d_in[11];

    int Nn = in_sizes[0] / 128;   // 50000
    int Ee = in_sizes[1] / 128;   // 800000
    float* out = (float*)d_out;

    // ws layout
    size_t need = 0;
    size_t off_qb  = need; need += (size_t)Nn * 128 * 2;   // qb bf16
    size_t off_kvb = need; need += (size_t)Nn * 256 * 2;   // kvb packed bf16
    size_t off_skb = need; need += (size_t)Nn * 128 * 4;   // skip f32
    size_t off_perm= need; need += (size_t)Ee * 4;         // perm
    size_t off_rp  = need; need += (size_t)(Nn + 1) * 4;   // rowptr
    size_t off_cnt = need; need += (size_t)Nn * 4;         // counts
    size_t off_cur = need; need += (size_t)Nn * 4;         // cursors
    size_t off_wt  = need; need += 5 * 16384 * 2;          // Wt5
    (void)need;

    char* ws = (char*)d_ws;
    short* qb    = (short*)(ws + off_qb);
    short* kvb   = (short*)(ws + off_kvb);
    float* skb   = (float*)(ws + off_skb);
    int*   perm  = (int*)(ws + off_perm);
    int*   rowptr= (int*)(ws + off_rp);
    int*   cnt   = (int*)(ws + off_cnt);
    int*   cursor= (int*)(ws + off_cur);
    short* Wt5   = (short*)(ws + off_wt);

    hipMemsetAsync(cnt, 0, (size_t)Nn * 4, stream);
    hipMemsetAsync(cursor, 0, (size_t)Nn * 4, stream);

    prep_w<<<(5 * 16384 + 255) / 256, 256, 0, stream>>>(Wq, Wk, Wv, We, Wsk, Wt5);
    hist_dst<<<(Ee + 255) / 256, 256, 0, stream>>>(eidx, cnt, Ee);
    scan_rowptr<<<1, 1024, 0, stream>>>(cnt, rowptr, Nn);
    fill_perm<<<(Ee + 255) / 256, 256, 0, stream>>>(eidx, rowptr, cursor, perm, Ee);
    node_proj<<<dim3((Nn + TILE_M - 1) / TILE_M, 4), 512, 0, stream>>>(
        x, Wt5, bq, bk, bv, bsk, qb, kvb, skb, Nn);
    fused_attn<<<(Nn + NPB - 1) / NPB, 512, 0, stream>>>(
        ea, Wt5, qb, kvb, eidx, perm, rowptr, skb, out, Nn, Ee);
}